// Round 1
// baseline (503.209 us; speedup 1.0000x reference)
//
#include <hip/hip_runtime.h>

// Problem constants (B=4, T=2048, D=1024, H=16, HD=64)
constexpr int NB  = 4;
constexpr int NT  = 2048;
constexpr int ND  = 1024;
constexpr int NH  = 16;
constexpr int NHD = 64;
constexpr int NM  = NB * NT;   // 8192 tokens

typedef unsigned short u16;
typedef __attribute__((ext_vector_type(8))) short  short8;  // 8 bf16 (4 VGPRs)
typedef __attribute__((ext_vector_type(4))) float  f32x4;   // MFMA acc

__device__ __forceinline__ u16 f2bf(float f) {
  unsigned u = __builtin_bit_cast(unsigned, f);
  u += 0x7FFFu + ((u >> 16) & 1u);   // round-to-nearest-even
  return (u16)(u >> 16);
}

// ---------------- cast f32 -> bf16, vectorized x4 ----------------
__global__ __launch_bounds__(256) void cast_kernel(const float* __restrict__ in,
                                                   u16* __restrict__ out, int n4) {
  int i = blockIdx.x * 256 + threadIdx.x;
  if (i >= n4) return;
  float4 v = ((const float4*)in)[i];
  ushort4 o;
  o.x = f2bf(v.x); o.y = f2bf(v.y); o.z = f2bf(v.z); o.w = f2bf(v.w);
  ((ushort4*)out)[i] = o;
}

// ---------------- QKV GEMM: y = x @ W^T, scatter to [B,H,T,HD] ----------------
// A [M,K] bf16 row-major, B(W) [N,K] bf16 row-major (NT GEMM).
// 128x128 tile, BK=32, 4 waves (2x2 of 64x64), mfma_f32_16x16x32_bf16.
__global__ __launch_bounds__(256) void gemm_qkv(
    const u16* __restrict__ xb,
    const u16* __restrict__ wqb, const u16* __restrict__ wkb, const u16* __restrict__ wvb,
    u16* __restrict__ Qb, u16* __restrict__ Kb, u16* __restrict__ Vb) {
  const int z = blockIdx.z;
  const u16* wsel = (z == 0) ? wqb : (z == 1) ? wkb : wvb;
  u16* osel      = (z == 0) ? Qb  : (z == 1) ? Kb  : Vb;
  const float scl = (z == 0) ? 0.125f : 1.0f;   // attention scale folded into Q

  const int row0 = blockIdx.x * 128;
  const int col0 = blockIdx.y * 128;
  const int tid  = threadIdx.x;
  const int lane = tid & 63, wid = tid >> 6;
  const int wm = wid >> 1, wn = wid & 1;
  const int li = lane & 15, hi = lane >> 4;

  __shared__ __align__(16) u16 lA[128 * 32];
  __shared__ __align__(16) u16 lB[128 * 32];

  f32x4 acc[4][4] = {};

  for (int k0 = 0; k0 < ND; k0 += 32) {
#pragma unroll
    for (int s = 0; s < 2; ++s) {                 // stage A and B tiles
      int eo = (s * 256 + tid) * 8;
      int r = eo >> 5, c = eo & 31;
      *(uint4*)&lA[eo] = *(const uint4*)&xb  [(size_t)(row0 + r) * ND + k0 + c];
      *(uint4*)&lB[eo] = *(const uint4*)&wsel[(size_t)(col0 + r) * ND + k0 + c];
    }
    __syncthreads();
    short8 a[4], b[4];
#pragma unroll
    for (int m = 0; m < 4; ++m)
      a[m] = *(const short8*)&lA[(wm * 64 + m * 16 + li) * 32 + hi * 8];
#pragma unroll
    for (int n = 0; n < 4; ++n)
      b[n] = *(const short8*)&lB[(wn * 64 + n * 16 + li) * 32 + hi * 8];
#pragma unroll
    for (int m = 0; m < 4; ++m)
#pragma unroll
      for (int n = 0; n < 4; ++n)
        acc[m][n] = __builtin_amdgcn_mfma_f32_16x16x32_bf16(a[m], b[n], acc[m][n], 0, 0, 0);
    __syncthreads();
  }

  // epilogue: C/D layout col=lane&15, row=(lane>>4)*4+reg [m89]
#pragma unroll
  for (int m = 0; m < 4; ++m)
#pragma unroll
    for (int n = 0; n < 4; ++n)
#pragma unroll
      for (int rg = 0; rg < 4; ++rg) {
        int row = row0 + wm * 64 + m * 16 + hi * 4 + rg;   // token index
        int col = col0 + wn * 64 + n * 16 + li;            // feature index
        float v = acc[m][n][rg] * scl;
        int b_ = row >> 11, t_ = row & (NT - 1);
        int h_ = col >> 6,  d_ = col & (NHD - 1);
        osel[(((size_t)(b_ * NH + h_)) * NT + t_) * NHD + d_] = f2bf(v);
      }
}

// ---------------- WO GEMM + residual: out = x + AO @ WO^T (f32 out) ----------------
__global__ __launch_bounds__(256) void gemm_wo(
    const u16* __restrict__ ao, const u16* __restrict__ wob,
    const float* __restrict__ x, float* __restrict__ y) {
  const int row0 = blockIdx.x * 128;
  const int col0 = blockIdx.y * 128;
  const int tid  = threadIdx.x;
  const int lane = tid & 63, wid = tid >> 6;
  const int wm = wid >> 1, wn = wid & 1;
  const int li = lane & 15, hi = lane >> 4;

  __shared__ __align__(16) u16 lA[128 * 32];
  __shared__ __align__(16) u16 lB[128 * 32];

  f32x4 acc[4][4] = {};

  for (int k0 = 0; k0 < ND; k0 += 32) {
#pragma unroll
    for (int s = 0; s < 2; ++s) {
      int eo = (s * 256 + tid) * 8;
      int r = eo >> 5, c = eo & 31;
      *(uint4*)&lA[eo] = *(const uint4*)&ao [(size_t)(row0 + r) * ND + k0 + c];
      *(uint4*)&lB[eo] = *(const uint4*)&wob[(size_t)(col0 + r) * ND + k0 + c];
    }
    __syncthreads();
    short8 a[4], b[4];
#pragma unroll
    for (int m = 0; m < 4; ++m)
      a[m] = *(const short8*)&lA[(wm * 64 + m * 16 + li) * 32 + hi * 8];
#pragma unroll
    for (int n = 0; n < 4; ++n)
      b[n] = *(const short8*)&lB[(wn * 64 + n * 16 + li) * 32 + hi * 8];
#pragma unroll
    for (int m = 0; m < 4; ++m)
#pragma unroll
      for (int n = 0; n < 4; ++n)
        acc[m][n] = __builtin_amdgcn_mfma_f32_16x16x32_bf16(a[m], b[n], acc[m][n], 0, 0, 0);
    __syncthreads();
  }

#pragma unroll
  for (int m = 0; m < 4; ++m)
#pragma unroll
    for (int n = 0; n < 4; ++n)
#pragma unroll
      for (int rg = 0; rg < 4; ++rg) {
        int row = row0 + wm * 64 + m * 16 + hi * 4 + rg;
        int col = col0 + wn * 64 + n * 16 + li;
        size_t idx = (size_t)row * ND + col;
        y[idx] = acc[m][n][rg] + x[idx];   // residual add
      }
}

// ---------------- causal flash attention ----------------
// grid (32 qblocks, 64 bh). Block = 4 waves; wave owns 16 q-rows.
// Q/K/V in [B,H,T,HD] bf16. AO out as [M, D] bf16 (token-major, head-scattered).
__global__ __launch_bounds__(256) void attn_kernel(
    const u16* __restrict__ Q, const u16* __restrict__ K, const u16* __restrict__ V,
    u16* __restrict__ AO) {
  const int qb  = blockIdx.x;           // 0..31
  const int bh  = blockIdx.y;           // 0..63
  const int tid = threadIdx.x;
  const int lane = tid & 63, wid = tid >> 6;
  const int li = lane & 15, hi = lane >> 4;
  const int q0 = qb * 64;
  const int r0 = q0 + wid * 16;         // wave's q rows r0..r0+15
  const size_t base = (size_t)bh * NT * NHD;

  __shared__ __align__(16) u16 lK [64 * 64];   // [krow][hd]
  __shared__ __align__(16) u16 lVT[64 * 64];   // [hd][krow] (transposed)
  __shared__ __align__(16) u16 lP [4 * 16 * 64];

  // Q fragments (A-operand): lane holds Q[r0+li][c*32 + hi*8 + e]
  short8 qf[2];
  {
    int qrow = r0 + li;
#pragma unroll
    for (int c = 0; c < 2; ++c)
      qf[c] = *(const short8*)&Q[base + (size_t)qrow * NHD + c * 32 + hi * 8];
  }

  f32x4 o[4] = {};
  float mr[4] = {-INFINITY, -INFINITY, -INFINITY, -INFINITY};
  float lr[4] = {0.f, 0.f, 0.f, 0.f};

  for (int kt = 0; kt <= qb; ++kt) {
    const size_t kb = base + (size_t)kt * 64 * NHD;
#pragma unroll
    for (int s = 0; s < 2; ++s) {                 // stage K linear, V transposed
      int eo = (s * 256 + tid) * 8;
      int r = eo >> 6, c = eo & 63;
      *(uint4*)&lK[eo] = *(const uint4*)&K[kb + r * NHD + c];
      union { uint4 v; u16 s16[8]; } uu;
      uu.v = *(const uint4*)&V[kb + r * NHD + c];
#pragma unroll
      for (int j = 0; j < 8; ++j) lVT[(c + j) * 64 + r] = uu.s16[j];
    }
    __syncthreads();

    // S = Q K^T (scale pre-folded into Q)
    f32x4 s[4] = {};
#pragma unroll
    for (int g = 0; g < 4; ++g)
#pragma unroll
      for (int c = 0; c < 2; ++c) {
        short8 kf = *(const short8*)&lK[(g * 16 + li) * 64 + c * 32 + hi * 8];
        s[g] = __builtin_amdgcn_mfma_f32_16x16x32_bf16(qf[c], kf, s[g], 0, 0, 0);
      }

    if (kt == qb) {                               // causal mask on diagonal tile
#pragma unroll
      for (int g = 0; g < 4; ++g)
#pragma unroll
        for (int rg = 0; rg < 4; ++rg) {
          int col = kt * 64 + g * 16 + li;
          int row = r0 + hi * 4 + rg;
          if (col > row) s[g][rg] = -INFINITY;
        }
    }

    // online softmax (row stats live in 16-lane group, per reg)
#pragma unroll
    for (int rg = 0; rg < 4; ++rg) {
      float mx = fmaxf(fmaxf(s[0][rg], s[1][rg]), fmaxf(s[2][rg], s[3][rg]));
#pragma unroll
      for (int off = 1; off < 16; off <<= 1) mx = fmaxf(mx, __shfl_xor(mx, off));
      float mnew = fmaxf(mr[rg], mx);
      float sc = __expf(mr[rg] - mnew);
      float rs = 0.f;
#pragma unroll
      for (int g = 0; g < 4; ++g) {
        float p = __expf(s[g][rg] - mnew);
        s[g][rg] = p;
        rs += p;
      }
#pragma unroll
      for (int off = 1; off < 16; off <<= 1) rs += __shfl_xor(rs, off);
      lr[rg] = lr[rg] * sc + rs;
      mr[rg] = mnew;
#pragma unroll
      for (int gd = 0; gd < 4; ++gd) o[gd][rg] *= sc;
    }

    // P -> LDS (bf16) to re-layout into A-operand
#pragma unroll
    for (int g = 0; g < 4; ++g)
#pragma unroll
      for (int rg = 0; rg < 4; ++rg)
        lP[wid * 1024 + (hi * 4 + rg) * 64 + g * 16 + li] = f2bf(s[g][rg]);

    short8 pa[2];
#pragma unroll
    for (int c = 0; c < 2; ++c)
      pa[c] = *(const short8*)&lP[wid * 1024 + li * 64 + c * 32 + hi * 8];

    // O += P V
#pragma unroll
    for (int gd = 0; gd < 4; ++gd)
#pragma unroll
      for (int c = 0; c < 2; ++c) {
        short8 vf = *(const short8*)&lVT[(gd * 16 + li) * 64 + c * 32 + hi * 8];
        o[gd] = __builtin_amdgcn_mfma_f32_16x16x32_bf16(pa[c], vf, o[gd], 0, 0, 0);
      }
    __syncthreads();
  }

  // epilogue: O /= l, write AO[token, h*64+hd]
  const int b_ = bh >> 4, h_ = bh & 15;
#pragma unroll
  for (int gd = 0; gd < 4; ++gd)
#pragma unroll
    for (int rg = 0; rg < 4; ++rg) {
      float v = o[gd][rg] / lr[rg];
      int trow = r0 + hi * 4 + rg;
      int col  = h_ * 64 + gd * 16 + li;
      AO[((size_t)(b_ * NT + trow)) * ND + col] = f2bf(v);
    }
}

// ---------------- RMSNorm in-place on d_out ----------------
__global__ __launch_bounds__(256) void rmsnorm_kernel(float* __restrict__ y,
                                                      const float* __restrict__ g) {
  const int row = blockIdx.x;
  const int tid = threadIdx.x;
  const int lane = tid & 63, wid = tid >> 6;
  float4 v = ((const float4*)(y + (size_t)row * ND))[tid];
  float ss = v.x * v.x + v.y * v.y + v.z * v.z + v.w * v.w;
#pragma unroll
  for (int off = 32; off; off >>= 1) ss += __shfl_down(ss, off);
  __shared__ float red[4];
  if (lane == 0) red[wid] = ss;
  __syncthreads();
  float tot = red[0] + red[1] + red[2] + red[3];
  float inv = rsqrtf(tot * (1.0f / (float)ND) + 1e-6f);
  float4 gg = ((const float4*)g)[tid];
  float4 o;
  o.x = v.x * inv * gg.x; o.y = v.y * inv * gg.y;
  o.z = v.z * inv * gg.z; o.w = v.w * inv * gg.w;
  ((float4*)(y + (size_t)row * ND))[tid] = o;
}

extern "C" void kernel_launch(void* const* d_in, const int* in_sizes, int n_in,
                              void* d_out, int out_size, void* d_ws, size_t ws_size,
                              hipStream_t stream) {
  const float* x  = (const float*)d_in[0];
  const float* wq = (const float*)d_in[1];
  const float* wk = (const float*)d_in[2];
  const float* wv = (const float*)d_in[3];
  const float* wo = (const float*)d_in[4];
  const float* ng = (const float*)d_in[5];
  float* out = (float*)d_out;

  char* ws = (char*)d_ws;
  u16* xb  = (u16*)(ws);                    // 16 MB  [M, D] bf16
  u16* wqb = (u16*)(ws + (16u << 20));      //  2 MB
  u16* wkb = (u16*)(ws + (18u << 20));
  u16* wvb = (u16*)(ws + (20u << 20));
  u16* wob = (u16*)(ws + (22u << 20));
  u16* Qb  = (u16*)(ws + (24u << 20));      // 16 MB  [B,H,T,HD]
  u16* Kb  = (u16*)(ws + (40u << 20));
  u16* Vb  = (u16*)(ws + (56u << 20));
  u16* AO  = (u16*)(ws + (72u << 20));      // 16 MB  [M, D]  (ends at 88 MB)

  cast_kernel<<<NM * ND / 4 / 256, 256, 0, stream>>>(x,  xb,  NM * ND / 4);
  cast_kernel<<<ND * ND / 4 / 256, 256, 0, stream>>>(wq, wqb, ND * ND / 4);
  cast_kernel<<<ND * ND / 4 / 256, 256, 0, stream>>>(wk, wkb, ND * ND / 4);
  cast_kernel<<<ND * ND / 4 / 256, 256, 0, stream>>>(wv, wvb, ND * ND / 4);
  cast_kernel<<<ND * ND / 4 / 256, 256, 0, stream>>>(wo, wob, ND * ND / 4);

  gemm_qkv<<<dim3(NM / 128, ND / 128, 3), 256, 0, stream>>>(xb, wqb, wkb, wvb, Qb, Kb, Vb);
  attn_kernel<<<dim3(NT / 64, NB * NH), 256, 0, stream>>>(Qb, Kb, Vb, AO);
  gemm_wo<<<dim3(NM / 128, ND / 128), 256, 0, stream>>>(AO, wob, x, out);
  rmsnorm_kernel<<<NM, 256, 0, stream>>>(out, ng);
}

// Round 2
// 315.246 us; speedup vs baseline: 1.5962x; 1.5962x over previous
//
#include <hip/hip_runtime.h>

// Problem constants (B=4, T=2048, D=1024, H=16, HD=64)
constexpr int NB  = 4;
constexpr int NT  = 2048;
constexpr int ND  = 1024;
constexpr int NH  = 16;
constexpr int NHD = 64;
constexpr int NM  = NB * NT;   // 8192 tokens

typedef unsigned short u16;
typedef __attribute__((ext_vector_type(8))) short  short8;  // 8 bf16 (4 VGPRs)
typedef __attribute__((ext_vector_type(4))) float  f32x4;   // MFMA acc

__device__ __forceinline__ u16 f2bf(float f) {
  unsigned u = __builtin_bit_cast(unsigned, f);
  u += 0x7FFFu + ((u >> 16) & 1u);   // round-to-nearest-even
  return (u16)(u >> 16);
}

// async global->LDS, 16B per lane. dst must be wave-uniform; lane i lands at dst + i*16B.
__device__ __forceinline__ void gll16(const u16* src, u16* dst) {
  __builtin_amdgcn_global_load_lds(
      (const __attribute__((address_space(1))) void*)src,
      (__attribute__((address_space(3))) void*)dst, 16, 0, 0);
}

// ---------------- cast f32 -> bf16, vectorized x4 ----------------
__global__ __launch_bounds__(256) void cast_kernel(const float* __restrict__ in,
                                                   u16* __restrict__ out, int n4) {
  int i = blockIdx.x * 256 + threadIdx.x;
  if (i >= n4) return;
  float4 v = ((const float4*)in)[i];
  ushort4 o;
  o.x = f2bf(v.x); o.y = f2bf(v.y); o.z = f2bf(v.z); o.w = f2bf(v.w);
  ((ushort4*)out)[i] = o;
}

// ---------------- QKV GEMM: y = x @ W^T ----------------
// Q,K scattered to [B,H,T,HD]; V scattered TRANSPOSED to [B,H,HD,T].
// 128x128 tile, BK=32, 4 waves (2x2 of 64x64), global_load_lds staging (m97 structure).
__global__ __launch_bounds__(256) void gemm_qkv(
    const u16* __restrict__ xb,
    const u16* __restrict__ wqb, const u16* __restrict__ wkb, const u16* __restrict__ wvb,
    u16* __restrict__ Qb, u16* __restrict__ Kb, u16* __restrict__ VTb) {
  const int z = blockIdx.z;
  const u16* wsel = (z == 0) ? wqb : (z == 1) ? wkb : wvb;
  u16* osel      = (z == 0) ? Qb  : (z == 1) ? Kb  : VTb;
  const float scl = (z == 0) ? 0.125f : 1.0f;   // attention scale folded into Q

  const int row0 = blockIdx.x * 128;
  const int col0 = blockIdx.y * 128;
  const int tid  = threadIdx.x;
  const int lane = tid & 63, wid = tid >> 6;
  const int wm = wid >> 1, wn = wid & 1;
  const int li = lane & 15, hi = lane >> 4;

  __shared__ __align__(16) u16 lA[128 * 32];
  __shared__ __align__(16) u16 lB[128 * 32];

  f32x4 acc[4][4] = {};
  const int rl = lane >> 2;   // 0..15 (row within 16-row slab)
  const int c8 = lane & 3;    // 8-elem chunk within 32-elem row

  for (int k0 = 0; k0 < ND; k0 += 32) {
#pragma unroll
    for (int h = 0; h < 2; ++h) {
      int r = wid * 32 + h * 16 + rl;
      gll16(&xb  [(size_t)(row0 + r) * ND + k0 + c8 * 8], &lA[(wid * 32 + h * 16) * 32]);
      gll16(&wsel[(size_t)(col0 + r) * ND + k0 + c8 * 8], &lB[(wid * 32 + h * 16) * 32]);
    }
    __syncthreads();
    short8 a[4], b[4];
#pragma unroll
    for (int m = 0; m < 4; ++m)
      a[m] = *(const short8*)&lA[(wm * 64 + m * 16 + li) * 32 + hi * 8];
#pragma unroll
    for (int n = 0; n < 4; ++n)
      b[n] = *(const short8*)&lB[(wn * 64 + n * 16 + li) * 32 + hi * 8];
#pragma unroll
    for (int m = 0; m < 4; ++m)
#pragma unroll
      for (int n = 0; n < 4; ++n)
        acc[m][n] = __builtin_amdgcn_mfma_f32_16x16x32_bf16(a[m], b[n], acc[m][n], 0, 0, 0);
    __syncthreads();
  }

  // epilogue: C/D layout col=lane&15, row=(lane>>4)*4+reg [m89]
#pragma unroll
  for (int m = 0; m < 4; ++m)
#pragma unroll
    for (int n = 0; n < 4; ++n)
#pragma unroll
      for (int rg = 0; rg < 4; ++rg) {
        int row = row0 + wm * 64 + m * 16 + hi * 4 + rg;   // token index
        int col = col0 + wn * 64 + n * 16 + li;            // feature index
        int b_ = row >> 11, t_ = row & (NT - 1);
        int h_ = col >> 6,  d_ = col & (NHD - 1);
        if (z == 2) {  // V^T layout [B,H,HD,T]
          osel[(((size_t)(b_ * NH + h_)) * NHD + d_) * NT + t_] = f2bf(acc[m][n][rg]);
        } else {
          osel[(((size_t)(b_ * NH + h_)) * NT + t_) * NHD + d_] = f2bf(acc[m][n][rg] * scl);
        }
      }
}

// ---------------- WO GEMM + residual: out = x + AO @ WO^T (f32 out) ----------------
__global__ __launch_bounds__(256) void gemm_wo(
    const u16* __restrict__ ao, const u16* __restrict__ wob,
    const float* __restrict__ x, float* __restrict__ y) {
  const int row0 = blockIdx.x * 128;
  const int col0 = blockIdx.y * 128;
  const int tid  = threadIdx.x;
  const int lane = tid & 63, wid = tid >> 6;
  const int wm = wid >> 1, wn = wid & 1;
  const int li = lane & 15, hi = lane >> 4;

  __shared__ __align__(16) u16 lA[128 * 32];
  __shared__ __align__(16) u16 lB[128 * 32];

  f32x4 acc[4][4] = {};
  const int rl = lane >> 2;
  const int c8 = lane & 3;

  for (int k0 = 0; k0 < ND; k0 += 32) {
#pragma unroll
    for (int h = 0; h < 2; ++h) {
      int r = wid * 32 + h * 16 + rl;
      gll16(&ao [(size_t)(row0 + r) * ND + k0 + c8 * 8], &lA[(wid * 32 + h * 16) * 32]);
      gll16(&wob[(size_t)(col0 + r) * ND + k0 + c8 * 8], &lB[(wid * 32 + h * 16) * 32]);
    }
    __syncthreads();
    short8 a[4], b[4];
#pragma unroll
    for (int m = 0; m < 4; ++m)
      a[m] = *(const short8*)&lA[(wm * 64 + m * 16 + li) * 32 + hi * 8];
#pragma unroll
    for (int n = 0; n < 4; ++n)
      b[n] = *(const short8*)&lB[(wn * 64 + n * 16 + li) * 32 + hi * 8];
#pragma unroll
    for (int m = 0; m < 4; ++m)
#pragma unroll
      for (int n = 0; n < 4; ++n)
        acc[m][n] = __builtin_amdgcn_mfma_f32_16x16x32_bf16(a[m], b[n], acc[m][n], 0, 0, 0);
    __syncthreads();
  }

#pragma unroll
  for (int m = 0; m < 4; ++m)
#pragma unroll
    for (int n = 0; n < 4; ++n)
#pragma unroll
      for (int rg = 0; rg < 4; ++rg) {
        int row = row0 + wm * 64 + m * 16 + hi * 4 + rg;
        int col = col0 + wn * 64 + n * 16 + li;
        size_t idx = (size_t)row * ND + col;
        y[idx] = acc[m][n][rg] + x[idx];   // residual add
      }
}

// ---------------- causal flash attention ----------------
// grid 2048 blocks; XCD-swizzled to (qb 0..31, bh 0..63). 4 waves; wave owns 16 q-rows.
// K in [B,H,T,HD]; V^T in [B,H,HD,T]. LDS: double-buffered K & V^T tiles, XOR chunk-swizzle.
__global__ __launch_bounds__(256) void attn_kernel(
    const u16* __restrict__ Q, const u16* __restrict__ K, const u16* __restrict__ VT,
    u16* __restrict__ AO) {
  // T1: XCD-aware swizzle (2048 % 8 == 0 -> bijective)
  const int nb  = gridDim.x * gridDim.y;           // 2048
  const int b0  = blockIdx.y * gridDim.x + blockIdx.x;
  const int L   = (b0 & 7) * (nb >> 3) + (b0 >> 3);
  const int qb  = L & 31;            // q-tile 0..31
  const int bh  = L >> 5;            // 0..63

  const int tid = threadIdx.x;
  const int lane = tid & 63, wid = tid >> 6;
  const int li = lane & 15, hi = lane >> 4;
  const int r0 = qb * 64 + wid * 16;         // wave's q rows
  const size_t bK = (size_t)bh * NT * NHD;   // K  [bh][t][d]
  const size_t bV = (size_t)bh * NHD * NT;   // VT [bh][d][t]

  __shared__ __align__(16) u16 lK [2][64 * 64];
  __shared__ __align__(16) u16 lVT[2][64 * 64];
  __shared__ __align__(16) u16 lP [4][16 * 64];

  const int rl = lane >> 3;   // 0..7
  const int sl = lane & 7;    // dest chunk slot

  // Q fragments (A-operand): lane holds Q[r0+li][c*32 + hi*8 + e]
  short8 qf[2];
#pragma unroll
  for (int c = 0; c < 2; ++c)
    qf[c] = *(const short8*)&Q[bK + (size_t)(r0 + li) * NHD + c * 32 + hi * 8];

  f32x4 o[4] = {};
  float mr[4] = {-INFINITY, -INFINITY, -INFINITY, -INFINITY};
  float lr[4] = {0.f, 0.f, 0.f, 0.f};

  // ---- stage tile kt into buffer buf (pre-swizzled source, linear LDS dest) ----
  auto stage = [&](int buf, int kt) {
#pragma unroll
    for (int h = 0; h < 2; ++h) {
      int r  = wid * 16 + h * 8 + rl;        // tile row 0..63
      int c8 = sl ^ (r & 7);                 // source chunk for this dest slot
      gll16(&K [bK + (size_t)(kt * 64 + r) * NHD + c8 * 8], &lK [buf][(wid * 16 + h * 8) * 64]);
      gll16(&VT[bV + (size_t)r * NT + kt * 64 + c8 * 8],    &lVT[buf][(wid * 16 + h * 8) * 64]);
    }
  };

  stage(0, 0);
  __syncthreads();
  int buf = 0;

  for (int kt = 0; kt <= qb; ++kt) {
    if (kt < qb) stage(buf ^ 1, kt + 1);     // T3-min: issue next tile before compute

    // S = Q K^T (scale pre-folded into Q); swizzled lK read
    f32x4 s[4] = {};
#pragma unroll
    for (int g = 0; g < 4; ++g)
#pragma unroll
      for (int c = 0; c < 2; ++c) {
        short8 kf = *(const short8*)&lK[buf][(g * 16 + li) * 64 + ((c * 4 + hi) ^ (li & 7)) * 8];
        s[g] = __builtin_amdgcn_mfma_f32_16x16x32_bf16(qf[c], kf, s[g], 0, 0, 0);
      }

    if (kt == qb) {                          // causal mask on diagonal tile
#pragma unroll
      for (int g = 0; g < 4; ++g)
#pragma unroll
        for (int rg = 0; rg < 4; ++rg) {
          int col = kt * 64 + g * 16 + li;
          int row = r0 + hi * 4 + rg;
          if (col > row) s[g][rg] = -INFINITY;
        }
    }

    // online softmax (row stats live in 16-lane group, per reg)
#pragma unroll
    for (int rg = 0; rg < 4; ++rg) {
      float mx = fmaxf(fmaxf(s[0][rg], s[1][rg]), fmaxf(s[2][rg], s[3][rg]));
#pragma unroll
      for (int off = 1; off < 16; off <<= 1) mx = fmaxf(mx, __shfl_xor(mx, off));
      float mnew = fmaxf(mr[rg], mx);
      float sc = __expf(mr[rg] - mnew);
      float rs = 0.f;
#pragma unroll
      for (int g = 0; g < 4; ++g) {
        float p = __expf(s[g][rg] - mnew);
        s[g][rg] = p;
        rs += p;
      }
#pragma unroll
      for (int off = 1; off < 16; off <<= 1) rs += __shfl_xor(rs, off);
      lr[rg] = lr[rg] * sc + rs;
      mr[rg] = mnew;
#pragma unroll
      for (int gd = 0; gd < 4; ++gd) o[gd][rg] *= sc;
    }

    // P -> LDS (per-wave, swizzled) to re-layout into A-operand
#pragma unroll
    for (int g = 0; g < 4; ++g)
#pragma unroll
      for (int rg = 0; rg < 4; ++rg) {
        int row  = hi * 4 + rg;
        int swzc = (g * 2 + (li >> 3)) ^ (row & 7);
        lP[wid][row * 64 + swzc * 8 + (li & 7)] = f2bf(s[g][rg]);
      }

    short8 pa[2];
#pragma unroll
    for (int c = 0; c < 2; ++c)
      pa[c] = *(const short8*)&lP[wid][li * 64 + ((c * 4 + hi) ^ (li & 7)) * 8];

    // O += P V   (V^T fragments from swizzled lVT)
#pragma unroll
    for (int gd = 0; gd < 4; ++gd)
#pragma unroll
      for (int c = 0; c < 2; ++c) {
        short8 vf = *(const short8*)&lVT[buf][(gd * 16 + li) * 64 + ((c * 4 + hi) ^ (li & 7)) * 8];
        o[gd] = __builtin_amdgcn_mfma_f32_16x16x32_bf16(pa[c], vf, o[gd], 0, 0, 0);
      }

    __syncthreads();
    buf ^= 1;
  }

  // epilogue: O /= l, write AO[token, h*64+hd]
  const int b_ = bh >> 4, h_ = bh & 15;
#pragma unroll
  for (int gd = 0; gd < 4; ++gd)
#pragma unroll
    for (int rg = 0; rg < 4; ++rg) {
      float v = o[gd][rg] / lr[rg];
      int trow = r0 + hi * 4 + rg;
      int col  = h_ * 64 + gd * 16 + li;
      AO[((size_t)(b_ * NT + trow)) * ND + col] = f2bf(v);
    }
}

// ---------------- RMSNorm in-place on d_out ----------------
__global__ __launch_bounds__(256) void rmsnorm_kernel(float* __restrict__ y,
                                                      const float* __restrict__ g) {
  const int row = blockIdx.x;
  const int tid = threadIdx.x;
  const int lane = tid & 63, wid = tid >> 6;
  float4 v = ((const float4*)(y + (size_t)row * ND))[tid];
  float ss = v.x * v.x + v.y * v.y + v.z * v.z + v.w * v.w;
#pragma unroll
  for (int off = 32; off; off >>= 1) ss += __shfl_down(ss, off);
  __shared__ float red[4];
  if (lane == 0) red[wid] = ss;
  __syncthreads();
  float tot = red[0] + red[1] + red[2] + red[3];
  float inv = rsqrtf(tot * (1.0f / (float)ND) + 1e-6f);
  float4 gg = ((const float4*)g)[tid];
  float4 o;
  o.x = v.x * inv * gg.x; o.y = v.y * inv * gg.y;
  o.z = v.z * inv * gg.z; o.w = v.w * inv * gg.w;
  ((float4*)(y + (size_t)row * ND))[tid] = o;
}

extern "C" void kernel_launch(void* const* d_in, const int* in_sizes, int n_in,
                              void* d_out, int out_size, void* d_ws, size_t ws_size,
                              hipStream_t stream) {
  const float* x  = (const float*)d_in[0];
  const float* wq = (const float*)d_in[1];
  const float* wk = (const float*)d_in[2];
  const float* wv = (const float*)d_in[3];
  const float* wo = (const float*)d_in[4];
  const float* ng = (const float*)d_in[5];
  float* out = (float*)d_out;

  char* ws = (char*)d_ws;
  u16* xb  = (u16*)(ws);                    // 16 MB  [M, D] bf16
  u16* wqb = (u16*)(ws + (16u << 20));      //  2 MB
  u16* wkb = (u16*)(ws + (18u << 20));
  u16* wvb = (u16*)(ws + (20u << 20));
  u16* wob = (u16*)(ws + (22u << 20));
  u16* Qb  = (u16*)(ws + (24u << 20));      // 16 MB  [B,H,T,HD]
  u16* Kb  = (u16*)(ws + (40u << 20));      // 16 MB  [B,H,T,HD]
  u16* VTb = (u16*)(ws + (56u << 20));      // 16 MB  [B,H,HD,T]  (transposed V)
  u16* AO  = (u16*)(ws + (72u << 20));      // 16 MB  [M, D]  (ends at 88 MB)

  cast_kernel<<<NM * ND / 4 / 256, 256, 0, stream>>>(x,  xb,  NM * ND / 4);
  cast_kernel<<<ND * ND / 4 / 256, 256, 0, stream>>>(wq, wqb, ND * ND / 4);
  cast_kernel<<<ND * ND / 4 / 256, 256, 0, stream>>>(wk, wkb, ND * ND / 4);
  cast_kernel<<<ND * ND / 4 / 256, 256, 0, stream>>>(wv, wvb, ND * ND / 4);
  cast_kernel<<<ND * ND / 4 / 256, 256, 0, stream>>>(wo, wob, ND * ND / 4);

  gemm_qkv<<<dim3(NM / 128, ND / 128, 3), 256, 0, stream>>>(xb, wqb, wkb, wvb, Qb, Kb, VTb);
  attn_kernel<<<dim3(NT / 64, NB * NH), 256, 0, stream>>>(Qb, Kb, VTb, AO);
  gemm_wo<<<dim3(NM / 128, ND / 128), 256, 0, stream>>>(AO, wob, x, out);
  rmsnorm_kernel<<<NM, 256, 0, stream>>>(out, ng);
}

// Round 4
// 240.643 us; speedup vs baseline: 2.0911x; 1.3100x over previous
//
#include <hip/hip_runtime.h>
#include <hip/hip_bf16.h>

// Problem constants (B=4, T=2048, D=1024, H=16, HD=64)
constexpr int NB  = 4;
constexpr int NT  = 2048;
constexpr int ND  = 1024;
constexpr int NH  = 16;
constexpr int NHD = 64;
constexpr int NM  = NB * NT;   // 8192 tokens

typedef unsigned short u16;
typedef __attribute__((ext_vector_type(8))) short  short8;  // 8 bf16 (4 VGPRs)
typedef __attribute__((ext_vector_type(4))) float  f32x4;   // MFMA acc

__device__ __forceinline__ u16 f2bf(float f) {
  unsigned u = __builtin_bit_cast(unsigned, f);
  u += 0x7FFFu + ((u >> 16) & 1u);   // round-to-nearest-even
  return (u16)(u >> 16);
}

// pack two f32 -> 2x bf16 in one dword (compiler emits v_cvt_pk_bf16_f32)
__device__ __forceinline__ unsigned pk2bf(float lo, float hi_) {
  float2 t; t.x = lo; t.y = hi_;
  __hip_bfloat162 h2 = __float22bfloat162_rn(t);
  unsigned u;
  __builtin_memcpy(&u, &h2, 4);
  return u;
}

// async global->LDS, 16B per lane. dst must be wave-uniform; lane i lands at dst + i*16B.
__device__ __forceinline__ void gll16(const u16* src, u16* dst) {
  __builtin_amdgcn_global_load_lds(
      (const __attribute__((address_space(1))) void*)src,
      (__attribute__((address_space(3))) void*)dst, 16, 0, 0);
}

// ---------------- cast f32 -> bf16, vectorized x4 ----------------
__global__ __launch_bounds__(256) void cast_kernel(const float* __restrict__ in,
                                                   u16* __restrict__ out, int n4) {
  int i = blockIdx.x * 256 + threadIdx.x;
  if (i >= n4) return;
  float4 v = ((const float4*)in)[i];
  ushort4 o;
  o.x = f2bf(v.x); o.y = f2bf(v.y); o.z = f2bf(v.z); o.w = f2bf(v.w);
  ((ushort4*)out)[i] = o;
}

// ---------------- QKV GEMM: y = x @ W^T ----------------
// Q,K scattered to [B,H,T,HD]; V scattered TRANSPOSED to [B,H,HD,T].
__global__ __launch_bounds__(256) void gemm_qkv(
    const u16* __restrict__ xb,
    const u16* __restrict__ wqb, const u16* __restrict__ wkb, const u16* __restrict__ wvb,
    u16* __restrict__ Qb, u16* __restrict__ Kb, u16* __restrict__ VTb) {
  const int z = blockIdx.z;
  const u16* wsel = (z == 0) ? wqb : (z == 1) ? wkb : wvb;
  u16* osel      = (z == 0) ? Qb  : (z == 1) ? Kb  : VTb;
  // attention scale + log2(e) folded into Q (softmax done in exp2 domain)
  const float scl = (z == 0) ? 0.125f * 1.44269504f : 1.0f;

  const int row0 = blockIdx.x * 128;
  const int col0 = blockIdx.y * 128;
  const int tid  = threadIdx.x;
  const int lane = tid & 63, wid = tid >> 6;
  const int wm = wid >> 1, wn = wid & 1;
  const int li = lane & 15, hi = lane >> 4;

  __shared__ __align__(16) u16 lA[128 * 32];
  __shared__ __align__(16) u16 lB[128 * 32];

  f32x4 acc[4][4] = {};
  const int rl = lane >> 2;   // 0..15 (row within 16-row slab)
  const int c8 = lane & 3;    // 8-elem chunk within 32-elem row

  for (int k0 = 0; k0 < ND; k0 += 32) {
#pragma unroll
    for (int h = 0; h < 2; ++h) {
      int r = wid * 32 + h * 16 + rl;
      gll16(&xb  [(size_t)(row0 + r) * ND + k0 + c8 * 8], &lA[(wid * 32 + h * 16) * 32]);
      gll16(&wsel[(size_t)(col0 + r) * ND + k0 + c8 * 8], &lB[(wid * 32 + h * 16) * 32]);
    }
    __syncthreads();
    short8 a[4], b[4];
#pragma unroll
    for (int m = 0; m < 4; ++m)
      a[m] = *(const short8*)&lA[(wm * 64 + m * 16 + li) * 32 + hi * 8];
#pragma unroll
    for (int n = 0; n < 4; ++n)
      b[n] = *(const short8*)&lB[(wn * 64 + n * 16 + li) * 32 + hi * 8];
#pragma unroll
    for (int m = 0; m < 4; ++m)
#pragma unroll
      for (int n = 0; n < 4; ++n)
        acc[m][n] = __builtin_amdgcn_mfma_f32_16x16x32_bf16(a[m], b[n], acc[m][n], 0, 0, 0);
    __syncthreads();
  }

  // epilogue: C/D layout col=lane&15, row=(lane>>4)*4+reg [m89]
#pragma unroll
  for (int m = 0; m < 4; ++m)
#pragma unroll
    for (int n = 0; n < 4; ++n)
#pragma unroll
      for (int rg = 0; rg < 4; ++rg) {
        int row = row0 + wm * 64 + m * 16 + hi * 4 + rg;   // token index
        int col = col0 + wn * 64 + n * 16 + li;            // feature index
        int b_ = row >> 11, t_ = row & (NT - 1);
        int h_ = col >> 6,  d_ = col & (NHD - 1);
        if (z == 2) {  // V^T layout [B,H,HD,T]
          osel[(((size_t)(b_ * NH + h_)) * NHD + d_) * NT + t_] = f2bf(acc[m][n][rg]);
        } else {
          osel[(((size_t)(b_ * NH + h_)) * NT + t_) * NHD + d_] = f2bf(acc[m][n][rg] * scl);
        }
      }
}

// ---------------- WO GEMM + residual: out = x + AO @ WO^T (f32 out) ----------------
__global__ __launch_bounds__(256) void gemm_wo(
    const u16* __restrict__ ao, const u16* __restrict__ wob,
    const float* __restrict__ x, float* __restrict__ y) {
  const int row0 = blockIdx.x * 128;
  const int col0 = blockIdx.y * 128;
  const int tid  = threadIdx.x;
  const int lane = tid & 63, wid = tid >> 6;
  const int wm = wid >> 1, wn = wid & 1;
  const int li = lane & 15, hi = lane >> 4;

  __shared__ __align__(16) u16 lA[128 * 32];
  __shared__ __align__(16) u16 lB[128 * 32];

  f32x4 acc[4][4] = {};
  const int rl = lane >> 2;
  const int c8 = lane & 3;

  for (int k0 = 0; k0 < ND; k0 += 32) {
#pragma unroll
    for (int h = 0; h < 2; ++h) {
      int r = wid * 32 + h * 16 + rl;
      gll16(&ao [(size_t)(row0 + r) * ND + k0 + c8 * 8], &lA[(wid * 32 + h * 16) * 32]);
      gll16(&wob[(size_t)(col0 + r) * ND + k0 + c8 * 8], &lB[(wid * 32 + h * 16) * 32]);
    }
    __syncthreads();
    short8 a[4], b[4];
#pragma unroll
    for (int m = 0; m < 4; ++m)
      a[m] = *(const short8*)&lA[(wm * 64 + m * 16 + li) * 32 + hi * 8];
#pragma unroll
    for (int n = 0; n < 4; ++n)
      b[n] = *(const short8*)&lB[(wn * 64 + n * 16 + li) * 32 + hi * 8];
#pragma unroll
    for (int m = 0; m < 4; ++m)
#pragma unroll
      for (int n = 0; n < 4; ++n)
        acc[m][n] = __builtin_amdgcn_mfma_f32_16x16x32_bf16(a[m], b[n], acc[m][n], 0, 0, 0);
    __syncthreads();
  }

#pragma unroll
  for (int m = 0; m < 4; ++m)
#pragma unroll
    for (int n = 0; n < 4; ++n)
#pragma unroll
      for (int rg = 0; rg < 4; ++rg) {
        int row = row0 + wm * 64 + m * 16 + hi * 4 + rg;
        int col = col0 + wn * 64 + n * 16 + li;
        size_t idx = (size_t)row * ND + col;
        y[idx] = acc[m][n][rg] + x[idx];   // residual add
      }
}

// ---------------- causal flash attention (swapped-operand softmax) ----------------
// grid 2048 blocks; XCD-swizzled. 4 waves; wave owns 16 q-rows (q-local = lane&15).
// S = mfma(K, Q): lane holds S[q=li][k=g*16+hi*4+rg] -> row stats are 2-shuffle reductions.
// O = mfma(V^T, P): lane holds O[q=li][d=gd*16+hi*4+rg] -> scalar 1/l per lane.
__global__ __launch_bounds__(256) void attn_kernel(
    const u16* __restrict__ Q, const u16* __restrict__ K, const u16* __restrict__ VT,
    u16* __restrict__ AO) {
  // T1: XCD-aware swizzle (2048 % 8 == 0 -> bijective)
  const int nb  = gridDim.x * gridDim.y;           // 2048
  const int b0  = blockIdx.y * gridDim.x + blockIdx.x;
  const int L   = (b0 & 7) * (nb >> 3) + (b0 >> 3);
  const int qb  = L & 31;            // q-tile 0..31
  const int bh  = L >> 5;            // 0..63

  const int tid = threadIdx.x;
  const int lane = tid & 63, wid = tid >> 6;
  const int li = lane & 15, hi = lane >> 4;
  const int r0 = qb * 64 + wid * 16;         // wave's q rows
  const int qrow = r0 + li;                  // this lane's q row
  const size_t bK = (size_t)bh * NT * NHD;   // K  [bh][t][d]
  const size_t bV = (size_t)bh * NHD * NT;   // VT [bh][d][t]

  __shared__ __align__(16) u16 lK [2][64 * 64];
  __shared__ __align__(16) u16 lVT[2][64 * 64];
  __shared__ __align__(16) u16 lP [4][16 * 64];

  const int rl = lane >> 3;   // 0..7
  const int sl = lane & 7;    // dest chunk slot

  // Q fragments (B-operand): lane holds Q[r0+li][c*32 + hi*8 + e]
  short8 qf[2];
#pragma unroll
  for (int c = 0; c < 2; ++c)
    qf[c] = *(const short8*)&Q[bK + (size_t)qrow * NHD + c * 32 + hi * 8];

  f32x4 o[4] = {};
  float mr = -INFINITY;   // running row max (exp2 domain), per-lane (q=li)
  float lr = 0.f;         // running row sum

  // ---- stage tile kt into buffer buf (pre-swizzled source, linear LDS dest) ----
  auto stage = [&](int buf, int kt) {
#pragma unroll
    for (int h = 0; h < 2; ++h) {
      int r  = wid * 16 + h * 8 + rl;        // tile row 0..63
      int c8 = sl ^ (r & 7);                 // source chunk for this dest slot
      gll16(&K [bK + (size_t)(kt * 64 + r) * NHD + c8 * 8], &lK [buf][(wid * 16 + h * 8) * 64]);
      gll16(&VT[bV + (size_t)r * NT + kt * 64 + c8 * 8],    &lVT[buf][(wid * 16 + h * 8) * 64]);
    }
  };

  stage(0, 0);
  __syncthreads();
  int buf = 0;

  const int pswz = (li & 7) << 1;   // P-LDS XOR swizzle (8B chunks, bit0 preserved)

  for (int kt = 0; kt <= qb; ++kt) {
    if (kt < qb) stage(buf ^ 1, kt + 1);     // issue next tile before compute

    // S^T = K Q^T : s[g][rg] = S[q=li][k = g*16 + hi*4 + rg]
    f32x4 s[4] = {};
#pragma unroll
    for (int g = 0; g < 4; ++g)
#pragma unroll
      for (int c = 0; c < 2; ++c) {
        short8 kf = *(const short8*)&lK[buf][(g * 16 + li) * 64 + ((c * 4 + hi) ^ (li & 7)) * 8];
        s[g] = __builtin_amdgcn_mfma_f32_16x16x32_bf16(kf, qf[c], s[g], 0, 0, 0);
      }

    if (kt == qb) {                          // causal mask on diagonal tile
#pragma unroll
      for (int g = 0; g < 4; ++g)
#pragma unroll
        for (int rg = 0; rg < 4; ++rg) {
          int kcol = kt * 64 + g * 16 + hi * 4 + rg;
          if (kcol > qrow) s[g][rg] = -INFINITY;
        }
    }

    // tile row max: 15 in-lane fmax + 2 shuffles
    float mg0 = fmaxf(fmaxf(s[0][0], s[0][1]), fmaxf(s[0][2], s[0][3]));
    float mg1 = fmaxf(fmaxf(s[1][0], s[1][1]), fmaxf(s[1][2], s[1][3]));
    float mg2 = fmaxf(fmaxf(s[2][0], s[2][1]), fmaxf(s[2][2], s[2][3]));
    float mg3 = fmaxf(fmaxf(s[3][0], s[3][1]), fmaxf(s[3][2], s[3][3]));
    float pmax = fmaxf(fmaxf(mg0, mg1), fmaxf(mg2, mg3));
    pmax = fmaxf(pmax, __shfl_xor(pmax, 16));
    pmax = fmaxf(pmax, __shfl_xor(pmax, 32));

    // T13 defer-max: only rescale when the tile max exceeds m by > 8 (exp2 domain)
    if (__any(pmax > mr + 8.f)) {
      float mnew = fmaxf(mr, pmax);
      float sc = __builtin_amdgcn_exp2f(mr - mnew);
      lr *= sc;
#pragma unroll
      for (int gd = 0; gd < 4; ++gd)
#pragma unroll
        for (int rg = 0; rg < 4; ++rg) o[gd][rg] *= sc;
      mr = mnew;
    }

    // P = exp2(S - m); row sum: 15 in-lane adds + 2 shuffles
    float rs = 0.f;
#pragma unroll
    for (int g = 0; g < 4; ++g)
#pragma unroll
      for (int rg = 0; rg < 4; ++rg) {
        float pv = __builtin_amdgcn_exp2f(s[g][rg] - mr);
        s[g][rg] = pv;
        rs += pv;
      }
    rs += __shfl_xor(rs, 16);
    rs += __shfl_xor(rs, 32);
    lr += rs;

    // P -> LDS as bf16 (4x ds_write_b64, XOR-swizzled 8B chunks, conflict-free)
#pragma unroll
    for (int g = 0; g < 4; ++g) {
      uint2 w;
      w.x = pk2bf(s[g][0], s[g][1]);
      w.y = pk2bf(s[g][2], s[g][3]);
      int k8s = (g * 4 + hi) ^ pswz;
      *(uint2*)&lP[wid][li * 64 + k8s * 4] = w;
    }

    // P as B-operand: lane reads P[q=li][c*32 + hi*8 .. +7]
    short8 pa[2];
#pragma unroll
    for (int c = 0; c < 2; ++c)
      pa[c] = *(const short8*)&lP[wid][li * 64 + ((c * 8 + hi * 2) ^ pswz) * 4];

    // O^T += V^T P^T : o[gd][rg] = O[q=li][d = gd*16 + hi*4 + rg]
#pragma unroll
    for (int gd = 0; gd < 4; ++gd)
#pragma unroll
      for (int c = 0; c < 2; ++c) {
        short8 vf = *(const short8*)&lVT[buf][(gd * 16 + li) * 64 + ((c * 4 + hi) ^ (li & 7)) * 8];
        o[gd] = __builtin_amdgcn_mfma_f32_16x16x32_bf16(vf, pa[c], o[gd], 0, 0, 0);
      }

    __syncthreads();
    buf ^= 1;
  }

  // epilogue: O /= l; pack 4 bf16 (8B) per gd and store
  const int b_ = bh >> 4, h_ = bh & 15;
  const float inv = 1.0f / lr;
  const size_t rowbase = ((size_t)(b_ * NT + qrow)) * ND + h_ * 64;
#pragma unroll
  for (int gd = 0; gd < 4; ++gd) {
    uint2 w;
    w.x = pk2bf(o[gd][0] * inv, o[gd][1] * inv);
    w.y = pk2bf(o[gd][2] * inv, o[gd][3] * inv);
    *(uint2*)&AO[rowbase + gd * 16 + hi * 4] = w;
  }
}

// ---------------- RMSNorm in-place on d_out ----------------
__global__ __launch_bounds__(256) void rmsnorm_kernel(float* __restrict__ y,
                                                      const float* __restrict__ g) {
  const int row = blockIdx.x;
  const int tid = threadIdx.x;
  const int lane = tid & 63, wid = tid >> 6;
  float4 v = ((const float4*)(y + (size_t)row * ND))[tid];
  float ss = v.x * v.x + v.y * v.y + v.z * v.z + v.w * v.w;
#pragma unroll
  for (int off = 32; off; off >>= 1) ss += __shfl_down(ss, off);
  __shared__ float red[4];
  if (lane == 0) red[wid] = ss;
  __syncthreads();
  float tot = red[0] + red[1] + red[2] + red[3];
  float inv = rsqrtf(tot * (1.0f / (float)ND) + 1e-6f);
  float4 gg = ((const float4*)g)[tid];
  float4 o;
  o.x = v.x * inv * gg.x; o.y = v.y * inv * gg.y;
  o.z = v.z * inv * gg.z; o.w = v.w * inv * gg.w;
  ((float4*)(y + (size_t)row * ND))[tid] = o;
}

extern "C" void kernel_launch(void* const* d_in, const int* in_sizes, int n_in,
                              void* d_out, int out_size, void* d_ws, size_t ws_size,
                              hipStream_t stream) {
  const float* x  = (const float*)d_in[0];
  const float* wq = (const float*)d_in[1];
  const float* wk = (const float*)d_in[2];
  const float* wv = (const float*)d_in[3];
  const float* wo = (const float*)d_in[4];
  const float* ng = (const float*)d_in[5];
  float* out = (float*)d_out;

  char* ws = (char*)d_ws;
  u16* xb  = (u16*)(ws);                    // 16 MB  [M, D] bf16
  u16* wqb = (u16*)(ws + (16u << 20));      //  2 MB
  u16* wkb = (u16*)(ws + (18u << 20));
  u16* wvb = (u16*)(ws + (20u << 20));
  u16* wob = (u16*)(ws + (22u << 20));
  u16* Qb  = (u16*)(ws + (24u << 20));      // 16 MB  [B,H,T,HD]
  u16* Kb  = (u16*)(ws + (40u << 20));      // 16 MB  [B,H,T,HD]
  u16* VTb = (u16*)(ws + (56u << 20));      // 16 MB  [B,H,HD,T]  (transposed V)
  u16* AO  = (u16*)(ws + (72u << 20));      // 16 MB  [M, D]  (ends at 88 MB)

  cast_kernel<<<NM * ND / 4 / 256, 256, 0, stream>>>(x,  xb,  NM * ND / 4);
  cast_kernel<<<ND * ND / 4 / 256, 256, 0, stream>>>(wq, wqb, ND * ND / 4);
  cast_kernel<<<ND * ND / 4 / 256, 256, 0, stream>>>(wk, wkb, ND * ND / 4);
  cast_kernel<<<ND * ND / 4 / 256, 256, 0, stream>>>(wv, wvb, ND * ND / 4);
  cast_kernel<<<ND * ND / 4 / 256, 256, 0, stream>>>(wo, wob, ND * ND / 4);

  gemm_qkv<<<dim3(NM / 128, ND / 128, 3), 256, 0, stream>>>(xb, wqb, wkb, wvb, Qb, Kb, VTb);
  attn_kernel<<<dim3(NT / 64, NB * NH), 256, 0, stream>>>(Qb, Kb, VTb, AO);
  gemm_wo<<<dim3(NM / 128, ND / 128), 256, 0, stream>>>(AO, wob, x, out);
  rmsnorm_kernel<<<NM, 256, 0, stream>>>(out, ng);
}